// Round 1
// baseline (14108.426 us; speedup 1.0000x reference)
//
#include <hip/hip_runtime.h>
#include <stdint.h>

// Problem constants (fixed by the reference):
#define Bq      64
#define Nq      256
#define Hq      8
#define DHq     64
#define TOTALq  16384    // B*N
#define NTq     131072   // H*TOTAL
#define Dq      512      // H*DH

// ---------------------------------------------------------------------------
// Graph structure kernels (head-independent: all heads share the edge list)
// ---------------------------------------------------------------------------

__global__ void count_deg_kernel(const int* __restrict__ dstp, int* __restrict__ cnt, int E) {
    int e = blockIdx.x * 256 + threadIdx.x;
    if (e < E) atomicAdd(&cnt[dstp[e]], 1);
}

__global__ void dinv_kernel(const int* __restrict__ cnt, float* __restrict__ dinv_n) {
    int v = blockIdx.x * 256 + threadIdx.x;
    if (v < TOTALq) {
        int c = cnt[v];
        dinv_n[v] = (c > 0) ? rsqrtf((float)c) : 0.0f;
    }
}

// Single block, 1024 threads, 16 elements each: exclusive scan of cnt -> off,
// off[TOTAL] = E.  Also zeroes cnt so it can be reused as the scatter cursor.
__global__ void scan_kernel(int* __restrict__ cnt, int* __restrict__ off) {
    __shared__ int tot[1024];
    int t = threadIdx.x;
    int base = t * 16;
    int loc[16];
    int s = 0;
#pragma unroll
    for (int i = 0; i < 16; ++i) { loc[i] = s; s += cnt[base + i]; }
    tot[t] = s;
    __syncthreads();
    for (int d = 1; d < 1024; d <<= 1) {
        int v = (t >= d) ? tot[t - d] : 0;
        __syncthreads();
        tot[t] += v;
        __syncthreads();
    }
    int tbase = (t == 0) ? 0 : tot[t - 1];
#pragma unroll
    for (int i = 0; i < 16; ++i) { off[base + i] = tbase + loc[i]; cnt[base + i] = 0; }
    if (t == 1023) off[TOTALq] = tot[1023];
}

__global__ void scatter_kernel(const int* __restrict__ srcp, const int* __restrict__ dstp,
                               const int* __restrict__ off, int* __restrict__ cur,
                               const float* __restrict__ dinv_n,
                               int* __restrict__ csr_src, float* __restrict__ csr_w, int E) {
    int e = blockIdx.x * 256 + threadIdx.x;
    if (e >= E) return;
    int d = dstp[e], s = srcp[e];
    int slot = atomicAdd(&cur[d], 1);
    int p = off[d] + slot;
    csr_src[p] = s;
    csr_w[p] = -(dinv_n[s] * dinv_n[d]);
}

// ---------------------------------------------------------------------------
// Coefficient kernel: one block per graph g = h*B + b (512 blocks, 256 thr)
// attn is (B,H,N,N); A[g] = attn[b,h]
// ---------------------------------------------------------------------------
__global__ void coeff_kernel(const float* __restrict__ attn,
                             const float* __restrict__ Wg, const float* __restrict__ bg,
                             const float* __restrict__ Wlin, const float* __restrict__ blin,
                             float* __restrict__ coeff) {
    __shared__ float dinv[Nq];
    __shared__ float red[16];  // 4 waves x 4 channels
    int g = blockIdx.x;
    int h = g >> 6;
    int b = g & 63;
    const float* A = attn + ((size_t)(b * Hq + h)) * (Nq * Nq);
    int j = threadIdx.x;

    // pass 1: column sums -> deg = colsum + 1 -> dinv = rsqrt(deg)
    float cs = 0.0f;
    for (int i = 0; i < Nq; ++i) cs += A[i * Nq + j];
    float dv = rsqrtf(cs + 1.0f);
    dinv[j] = dv;
    __syncthreads();

    // pass 2: s[j] = (dinv[j]*1 + sum_i dinv[i]*A[i][j]) * dinv[j]
    float sj = dv;  // identity (A_hat diagonal) contribution
    for (int i = 0; i < Nq; ++i) sj += dinv[i] * A[i * Nq + j];
    sj *= dv;

    // x_c = tanh(s*w_row + b_gcn); reduce mean over the 256 columns
    float xc[4];
#pragma unroll
    for (int c = 0; c < 4; ++c) {
        float wr = Wg[0 * 4 + c] + Wg[1 * 4 + c] + Wg[2 * 4 + c] + Wg[3 * 4 + c];
        xc[c] = tanhf(sj * wr + bg[c]);
    }
    int lane = j & 63, wv = j >> 6;
#pragma unroll
    for (int c = 0; c < 4; ++c) {
        float v = xc[c];
#pragma unroll
        for (int o = 32; o >= 1; o >>= 1) v += __shfl_down(v, o, 64);
        if (lane == 0) red[wv * 4 + c] = v;
    }
    __syncthreads();
    if (j < 4) {
        float gap[4];
#pragma unroll
        for (int c = 0; c < 4; ++c)
            gap[c] = (red[0 + c] + red[4 + c] + red[8 + c] + red[12 + c]) * (1.0f / 256.0f);
        float v = blin[j];
#pragma unroll
        for (int c = 0; c < 4; ++c) v += gap[c] * Wlin[c * 4 + j];
        coeff[g * 4 + j] = v;
    }
}

// ---------------------------------------------------------------------------
// Chebyshev kernels: one wave per (h, node); lane = dh.
// x0[h*TOTAL+node][dh] = oeh[(node*H + h)*DH + dh]   (oeh = out_each_head)
// filtered written in final-GEMM layout: filt[(n*B+b)*D + h*DH + dh]
// ---------------------------------------------------------------------------

// k = 0,1:  T1 = prop(x0);  filt = c0*(x0@W0) + c1*(T1@W1)
__global__ void cheb01_kernel(const float* __restrict__ oeh,
                              const int* __restrict__ csr_off, const int* __restrict__ csr_src,
                              const float* __restrict__ csr_w,
                              const float* __restrict__ coeff, const float* __restrict__ Wch,
                              float* __restrict__ T1, float* __restrict__ filt) {
    __shared__ float Wl[2 * DHq * DHq];  // W0, W1 (32 KB)
    int tid = threadIdx.x;
#pragma unroll
    for (int it = 0; it < 32; ++it) Wl[it * 256 + tid] = Wch[it * 256 + tid];
    __syncthreads();

    int wid = blockIdx.x * 4 + (tid >> 6);  // 0..NT-1
    int lane = tid & 63;
    int h = wid >> 14;          // / TOTAL
    int node = wid & 16383;     // % TOTAL
    int b = node >> 8;

    float x0 = oeh[((size_t)(node * Hq + h)) * DHq + lane];
    int e0 = csr_off[node], e1 = csr_off[node + 1];
    float y = 0.0f;
    for (int e = e0; e < e1; ++e) {
        int s = csr_src[e];
        float w = csr_w[e];
        y += w * oeh[((size_t)(s * Hq + h)) * DHq + lane];
    }
    T1[((size_t)(h * TOTALq + node)) * DHq + lane] = y;

    float c0 = coeff[(h * Bq + b) * 4 + 0];
    float c1 = coeff[(h * Bq + b) * 4 + 1];
    float m0 = 0.0f, m1 = 0.0f;
#pragma unroll
    for (int jj = 0; jj < DHq; ++jj) {
        float a0 = __shfl(x0, jj, 64);
        float a1 = __shfl(y, jj, 64);
        m0 += a0 * Wl[jj * DHq + lane];
        m1 += a1 * Wl[DHq * DHq + jj * DHq + lane];
    }
    int n = node & 255;
    int r = n * Bq + b;
    filt[(size_t)r * Dq + h * DHq + lane] = c0 * m0 + c1 * m1;
}

// k = 2,3:  Tn = 2*prop(Tcur) - Tprev;  filt += ck*(Tn@Wk) (+ b_cheb on last)
__global__ void chebstep_kernel(const float* __restrict__ oeh,
                                const int* __restrict__ csr_off, const int* __restrict__ csr_src,
                                const float* __restrict__ csr_w,
                                const float* __restrict__ coeff, const float* __restrict__ Wk,
                                const float* __restrict__ Tcur, const float* __restrict__ Tprev,
                                float* __restrict__ Tnext, const float* __restrict__ bch,
                                float* __restrict__ filt,
                                int k, int prev_is_x0, int store_next, int add_bias) {
    __shared__ float Wl[DHq * DHq];  // 16 KB
    int tid = threadIdx.x;
#pragma unroll
    for (int it = 0; it < 16; ++it) Wl[it * 256 + tid] = Wk[it * 256 + tid];
    __syncthreads();

    int wid = blockIdx.x * 4 + (tid >> 6);
    int lane = tid & 63;
    int h = wid >> 14;
    int node = wid & 16383;
    int b = node >> 8;

    int e0 = csr_off[node], e1 = csr_off[node + 1];
    float y = 0.0f;
    for (int e = e0; e < e1; ++e) {
        int s = csr_src[e];
        float w = csr_w[e];
        y += w * Tcur[((size_t)(h * TOTALq + s)) * DHq + lane];
    }
    float tp = prev_is_x0 ? oeh[((size_t)(node * Hq + h)) * DHq + lane]
                          : Tprev[((size_t)(h * TOTALq + node)) * DHq + lane];
    float tn = 2.0f * y - tp;
    if (store_next) Tnext[((size_t)(h * TOTALq + node)) * DHq + lane] = tn;

    float ck = coeff[(h * Bq + b) * 4 + k];
    float m = 0.0f;
#pragma unroll
    for (int jj = 0; jj < DHq; ++jj) {
        float a = __shfl(tn, jj, 64);
        m += a * Wl[jj * DHq + lane];
    }
    int n = node & 255;
    int r = n * Bq + b;
    float add = ck * m + (add_bias ? bch[lane] : 0.0f);
    filt[(size_t)r * Dq + h * DHq + lane] += add;
}

// ---------------------------------------------------------------------------
// Final GEMM (M=16384, K=1024, N=512) + fused LayerNorm.
// Block: 256 threads, 32 rows, full 512 cols; dynamic LDS 64 KB.
// A row r = n*B+b: first 512 cols from output[r*512+..], next 512 from filt.
// ---------------------------------------------------------------------------
__global__ void gemm_ln_kernel(const float* __restrict__ outp, const float* __restrict__ filt,
                               const float* __restrict__ Wc, const float* __restrict__ bcat,
                               const float* __restrict__ gamma, const float* __restrict__ beta,
                               float* __restrict__ out) {
    extern __shared__ float sm[];          // 16384 floats (64 KB)
    float* Wl = sm;                        // [16][512] during GEMM
    float* Al = sm + 8192;                 // [32][16]  during GEMM
    const int tid = threadIdx.x;
    const int r0 = blockIdx.x * 32;

    float acc0[32], acc1[32];
#pragma unroll
    for (int m = 0; m < 32; ++m) { acc0[m] = 0.0f; acc1[m] = 0.0f; }

    for (int kc = 0; kc < 1024; kc += 16) {
        __syncthreads();
        // stage A tile: 32 rows x 16 k  (512 elements)
        {
            int idx = tid;
#pragma unroll
            for (int it = 0; it < 2; ++it, idx += 256) {
                int m = idx >> 4, kk = idx & 15;
                int jcol = kc + kk;
                int r = r0 + m;
                float v = (jcol < 512) ? outp[(size_t)r * 512 + jcol]
                                       : filt[(size_t)r * 512 + (jcol - 512)];
                Al[m * 16 + kk] = v;
            }
        }
        // stage W tile: 16 k x 512 cols (8192 elements)
#pragma unroll
        for (int it = 0; it < 32; ++it) {
            int idx = it * 256 + tid;
            int jj = idx >> 9, dcol = idx & 511;
            Wl[idx] = Wc[(size_t)(kc + jj) * 512 + dcol];
        }
        __syncthreads();
#pragma unroll
        for (int kk = 0; kk < 16; ++kk) {
            float w0 = Wl[kk * 512 + tid];
            float w1 = Wl[kk * 512 + tid + 256];
#pragma unroll
            for (int m = 0; m < 32; ++m) {
                float a = Al[m * 16 + kk];
                acc0[m] += a * w0;
                acc1[m] += a * w1;
            }
        }
    }
    __syncthreads();
    // write C tile (with bias) to LDS for the LayerNorm pass
    float b0 = bcat[tid], b1 = bcat[tid + 256];
#pragma unroll
    for (int m = 0; m < 32; ++m) {
        sm[m * 512 + tid] = acc0[m] + b0;
        sm[m * 512 + tid + 256] = acc1[m] + b1;
    }
    __syncthreads();
    // LayerNorm: wave wv handles rows wv*8 .. wv*8+7
    const int wv = tid >> 6, lane = tid & 63;
    for (int m8 = 0; m8 < 8; ++m8) {
        int m = wv * 8 + m8;
        float s = 0.0f, ss = 0.0f;
#pragma unroll
        for (int i = 0; i < 8; ++i) {
            float v = sm[m * 512 + i * 64 + lane];
            s += v; ss += v * v;
        }
#pragma unroll
        for (int o = 32; o >= 1; o >>= 1) {
            s += __shfl_down(s, o, 64);
            ss += __shfl_down(ss, o, 64);
        }
        s = __shfl(s, 0, 64);
        ss = __shfl(ss, 0, 64);
        float mu = s * (1.0f / 512.0f);
        float var = ss * (1.0f / 512.0f) - mu * mu;
        float rs = rsqrtf(var + 1e-5f);
        int r = r0 + m;
#pragma unroll
        for (int i = 0; i < 8; ++i) {
            int d = i * 64 + lane;
            float v = (sm[m * 512 + d] - mu) * rs * gamma[d] + beta[d];
            out[(size_t)r * 512 + d] = v;
        }
    }
}

// ---------------------------------------------------------------------------
// Launch
// ---------------------------------------------------------------------------
extern "C" void kernel_launch(void* const* d_in, const int* in_sizes, int n_in,
                              void* d_out, int out_size, void* d_ws, size_t ws_size,
                              hipStream_t stream) {
    const float* output       = (const float*)d_in[0];
    const float* attn         = (const float*)d_in[1];
    const float* oeh          = (const float*)d_in[2];
    const int*   edge_index   = (const int*)d_in[3];
    // d_in[4] feature_indices, d_in[5] batch: identity layouts, unused
    const float* W_gcn        = (const float*)d_in[6];
    const float* b_gcn        = (const float*)d_in[7];
    const float* W_lin        = (const float*)d_in[8];
    const float* b_lin        = (const float*)d_in[9];
    const float* W_cheb       = (const float*)d_in[10];
    const float* b_cheb       = (const float*)d_in[11];
    const float* W_cat        = (const float*)d_in[12];
    const float* b_cat        = (const float*)d_in[13];
    const float* gamma        = (const float*)d_in[14];
    const float* beta         = (const float*)d_in[15];
    float* out = (float*)d_out;

    const int E = in_sizes[3] / 2;               // 262144 base edges
    const int* srcp = edge_index;
    const int* dstp = edge_index + E;

    // workspace carve-up (256-byte aligned)
    uint8_t* ws = (uint8_t*)d_ws;
    size_t cur = 0;
    auto alloc = [&](size_t bytes) -> void* {
        void* p = ws + cur;
        cur += (bytes + 255) & ~(size_t)255;
        return p;
    };
    int*   cnt     = (int*)alloc(TOTALq * sizeof(int));
    int*   off     = (int*)alloc((TOTALq + 1) * sizeof(int));
    float* dinv_n  = (float*)alloc(TOTALq * sizeof(float));
    int*   csr_src = (int*)alloc((size_t)E * sizeof(int));
    float* csr_w   = (float*)alloc((size_t)E * sizeof(float));
    float* coeff   = (float*)alloc(Hq * Bq * 4 * sizeof(float));
    float* T1      = (float*)alloc((size_t)NTq * DHq * sizeof(float));
    float* T2      = (float*)alloc((size_t)NTq * DHq * sizeof(float));
    float* filt    = (float*)alloc((size_t)TOTALq * Dq * sizeof(float));
    (void)ws_size; (void)n_in; (void)out_size;

    hipMemsetAsync(cnt, 0, TOTALq * sizeof(int), stream);
    count_deg_kernel<<<(E + 255) / 256, 256, 0, stream>>>(dstp, cnt, E);
    dinv_kernel<<<TOTALq / 256, 256, 0, stream>>>(cnt, dinv_n);
    scan_kernel<<<1, 1024, 0, stream>>>(cnt, off);
    scatter_kernel<<<(E + 255) / 256, 256, 0, stream>>>(srcp, dstp, off, cnt, dinv_n,
                                                        csr_src, csr_w, E);
    coeff_kernel<<<Hq * Bq, 256, 0, stream>>>(attn, W_gcn, b_gcn, W_lin, b_lin, coeff);

    const int cheb_blocks = NTq / 4;  // 4 waves per 256-thread block
    cheb01_kernel<<<cheb_blocks, 256, 0, stream>>>(oeh, off, csr_src, csr_w, coeff,
                                                   W_cheb, T1, filt);
    // k=2: T2 = 2*prop(T1) - x0
    chebstep_kernel<<<cheb_blocks, 256, 0, stream>>>(oeh, off, csr_src, csr_w, coeff,
                                                     W_cheb + 2 * DHq * DHq,
                                                     T1, nullptr, T2, b_cheb, filt,
                                                     2, 1, 1, 0);
    // k=3: T3 = 2*prop(T2) - T1 (not stored); add b_cheb
    chebstep_kernel<<<cheb_blocks, 256, 0, stream>>>(oeh, off, csr_src, csr_w, coeff,
                                                     W_cheb + 3 * DHq * DHq,
                                                     T2, T1, nullptr, b_cheb, filt,
                                                     3, 0, 0, 1);

    gemm_ln_kernel<<<TOTALq / 32, 256, 65536, stream>>>(output, filt, W_cat, b_cat,
                                                        gamma, beta, out);
}

// Round 2
// 1605.993 us; speedup vs baseline: 8.7849x; 8.7849x over previous
//
#include <hip/hip_runtime.h>
#include <stdint.h>

// Problem constants (fixed by the reference):
#define Bq      64
#define Nq      256
#define Hq      8
#define DHq     64
#define TOTALq  16384    // B*N
#define NTq     131072   // H*TOTAL
#define Dq      512      // H*DH

typedef __attribute__((ext_vector_type(8))) short short8;
typedef __attribute__((ext_vector_type(4))) float floatx4;

__device__ __forceinline__ unsigned short f2bf(float f) {
    union { float f; unsigned int u; } c; c.f = f;
    unsigned int u = c.u;
    return (unsigned short)((u + 0x7fffu + ((u >> 16) & 1u)) >> 16);
}

// ---------------------------------------------------------------------------
// Graph structure kernels (head-independent: all heads share the edge list)
// ---------------------------------------------------------------------------

__global__ void count_deg_kernel(const int* __restrict__ dstp, int* __restrict__ cnt, int E) {
    int e = blockIdx.x * 256 + threadIdx.x;
    if (e < E) atomicAdd(&cnt[dstp[e]], 1);
}

__global__ void dinv_kernel(const int* __restrict__ cnt, float* __restrict__ dinv_n) {
    int v = blockIdx.x * 256 + threadIdx.x;
    if (v < TOTALq) {
        int c = cnt[v];
        dinv_n[v] = (c > 0) ? rsqrtf((float)c) : 0.0f;
    }
}

// Single block, 1024 threads, 16 elements each: exclusive scan of cnt -> off,
// off[TOTAL] = E.  Also zeroes cnt so it can be reused as the scatter cursor.
__global__ void scan_kernel(int* __restrict__ cnt, int* __restrict__ off) {
    __shared__ int tot[1024];
    int t = threadIdx.x;
    int base = t * 16;
    int loc[16];
    int s = 0;
#pragma unroll
    for (int i = 0; i < 16; ++i) { loc[i] = s; s += cnt[base + i]; }
    tot[t] = s;
    __syncthreads();
    for (int d = 1; d < 1024; d <<= 1) {
        int v = (t >= d) ? tot[t - d] : 0;
        __syncthreads();
        tot[t] += v;
        __syncthreads();
    }
    int tbase = (t == 0) ? 0 : tot[t - 1];
#pragma unroll
    for (int i = 0; i < 16; ++i) { off[base + i] = tbase + loc[i]; cnt[base + i] = 0; }
    if (t == 1023) off[TOTALq] = tot[1023];
}

__global__ void scatter_kernel(const int* __restrict__ srcp, const int* __restrict__ dstp,
                               const int* __restrict__ off, int* __restrict__ cur,
                               const float* __restrict__ dinv_n,
                               int* __restrict__ csr_src, float* __restrict__ csr_w, int E) {
    int e = blockIdx.x * 256 + threadIdx.x;
    if (e >= E) return;
    int d = dstp[e], s = srcp[e];
    int slot = atomicAdd(&cur[d], 1);
    int p = off[d] + slot;
    csr_src[p] = s;
    csr_w[p] = -(dinv_n[s] * dinv_n[d]);
}

// ---------------------------------------------------------------------------
// Coefficient kernel: one block per graph g = h*B + b (512 blocks, 256 thr)
// ---------------------------------------------------------------------------
__global__ void coeff_kernel(const float* __restrict__ attn,
                             const float* __restrict__ Wg, const float* __restrict__ bg,
                             const float* __restrict__ Wlin, const float* __restrict__ blin,
                             float* __restrict__ coeff) {
    __shared__ float dinv[Nq];
    __shared__ float red[16];  // 4 waves x 4 channels
    int g = blockIdx.x;
    int h = g >> 6;
    int b = g & 63;
    const float* A = attn + ((size_t)(b * Hq + h)) * (Nq * Nq);
    int j = threadIdx.x;

    float cs = 0.0f;
    for (int i = 0; i < Nq; ++i) cs += A[i * Nq + j];
    float dv = rsqrtf(cs + 1.0f);
    dinv[j] = dv;
    __syncthreads();

    float sj = dv;
    for (int i = 0; i < Nq; ++i) sj += dinv[i] * A[i * Nq + j];
    sj *= dv;

    float xc[4];
#pragma unroll
    for (int c = 0; c < 4; ++c) {
        float wr = Wg[0 * 4 + c] + Wg[1 * 4 + c] + Wg[2 * 4 + c] + Wg[3 * 4 + c];
        xc[c] = tanhf(sj * wr + bg[c]);
    }
    int lane = j & 63, wv = j >> 6;
#pragma unroll
    for (int c = 0; c < 4; ++c) {
        float v = xc[c];
#pragma unroll
        for (int o = 32; o >= 1; o >>= 1) v += __shfl_down(v, o, 64);
        if (lane == 0) red[wv * 4 + c] = v;
    }
    __syncthreads();
    if (j < 4) {
        float gap[4];
#pragma unroll
        for (int c = 0; c < 4; ++c)
            gap[c] = (red[0 + c] + red[4 + c] + red[8 + c] + red[12 + c]) * (1.0f / 256.0f);
        float v = blin[j];
#pragma unroll
        for (int c = 0; c < 4; ++c) v += gap[c] * Wlin[c * 4 + j];
        coeff[g * 4 + j] = v;
    }
}

// ---------------------------------------------------------------------------
// Chebyshev kernels: one wave per (h, node); lane = dh.
// ---------------------------------------------------------------------------

__global__ void cheb01_kernel(const float* __restrict__ oeh,
                              const int* __restrict__ csr_off, const int* __restrict__ csr_src,
                              const float* __restrict__ csr_w,
                              const float* __restrict__ coeff, const float* __restrict__ Wch,
                              float* __restrict__ T1, float* __restrict__ filt) {
    __shared__ float Wl[2 * DHq * DHq];  // W0, W1 (32 KB)
    int tid = threadIdx.x;
#pragma unroll
    for (int it = 0; it < 32; ++it) Wl[it * 256 + tid] = Wch[it * 256 + tid];
    __syncthreads();

    int wid = blockIdx.x * 4 + (tid >> 6);  // 0..NT-1
    int lane = tid & 63;
    int h = wid >> 14;
    int node = wid & 16383;
    int b = node >> 8;

    float x0 = oeh[((size_t)(node * Hq + h)) * DHq + lane];
    int e0 = csr_off[node], e1 = csr_off[node + 1];
    float y = 0.0f;
    for (int e = e0; e < e1; ++e) {
        int s = csr_src[e];
        float w = csr_w[e];
        y += w * oeh[((size_t)(s * Hq + h)) * DHq + lane];
    }
    T1[((size_t)(h * TOTALq + node)) * DHq + lane] = y;

    float c0 = coeff[(h * Bq + b) * 4 + 0];
    float c1 = coeff[(h * Bq + b) * 4 + 1];
    float m0 = 0.0f, m1 = 0.0f;
#pragma unroll
    for (int jj = 0; jj < DHq; ++jj) {
        float a0 = __shfl(x0, jj, 64);
        float a1 = __shfl(y, jj, 64);
        m0 += a0 * Wl[jj * DHq + lane];
        m1 += a1 * Wl[DHq * DHq + jj * DHq + lane];
    }
    int n = node & 255;
    int r = n * Bq + b;
    filt[(size_t)r * Dq + h * DHq + lane] = c0 * m0 + c1 * m1;
}

__global__ void chebstep_kernel(const float* __restrict__ oeh,
                                const int* __restrict__ csr_off, const int* __restrict__ csr_src,
                                const float* __restrict__ csr_w,
                                const float* __restrict__ coeff, const float* __restrict__ Wk,
                                const float* __restrict__ Tcur, const float* __restrict__ Tprev,
                                float* __restrict__ Tnext, const float* __restrict__ bch,
                                float* __restrict__ filt,
                                int k, int prev_is_x0, int store_next, int add_bias) {
    __shared__ float Wl[DHq * DHq];  // 16 KB
    int tid = threadIdx.x;
#pragma unroll
    for (int it = 0; it < 16; ++it) Wl[it * 256 + tid] = Wk[it * 256 + tid];
    __syncthreads();

    int wid = blockIdx.x * 4 + (tid >> 6);
    int lane = tid & 63;
    int h = wid >> 14;
    int node = wid & 16383;
    int b = node >> 8;

    int e0 = csr_off[node], e1 = csr_off[node + 1];
    float y = 0.0f;
    for (int e = e0; e < e1; ++e) {
        int s = csr_src[e];
        float w = csr_w[e];
        y += w * Tcur[((size_t)(h * TOTALq + s)) * DHq + lane];
    }
    float tp = prev_is_x0 ? oeh[((size_t)(node * Hq + h)) * DHq + lane]
                          : Tprev[((size_t)(h * TOTALq + node)) * DHq + lane];
    float tn = 2.0f * y - tp;
    if (store_next) Tnext[((size_t)(h * TOTALq + node)) * DHq + lane] = tn;

    float ck = coeff[(h * Bq + b) * 4 + k];
    float m = 0.0f;
#pragma unroll
    for (int jj = 0; jj < DHq; ++jj) {
        float a = __shfl(tn, jj, 64);
        m += a * Wl[jj * DHq + lane];
    }
    int n = node & 255;
    int r = n * Bq + b;
    float add = ck * m + (add_bias ? bch[lane] : 0.0f);
    filt[(size_t)r * Dq + h * DHq + lane] += add;
}

// ---------------------------------------------------------------------------
// W_cat transpose+convert: W (1024x512 fp32, row=k) -> Wt (512x1024 bf16, row=col)
// grid (16, 8): 64x64 tiles; 256 threads.
// ---------------------------------------------------------------------------
__global__ void wt_kernel(const float* __restrict__ W, unsigned short* __restrict__ Wt) {
    __shared__ float tile[64][65];
    int t = threadIdx.x;
    int k0 = blockIdx.x * 64;
    int c0 = blockIdx.y * 64;
#pragma unroll
    for (int it = 0; it < 16; ++it) {
        int idx = it * 256 + t;
        int kr = idx >> 6, cc = idx & 63;
        tile[kr][cc] = W[(size_t)(k0 + kr) * 512 + c0 + cc];
    }
    __syncthreads();
#pragma unroll
    for (int it = 0; it < 16; ++it) {
        int idx = it * 256 + t;
        int cr = idx >> 6, kk = idx & 63;
        Wt[(size_t)(c0 + cr) * 1024 + k0 + kk] = f2bf(tile[kk][cr]);
    }
}

// ---------------------------------------------------------------------------
// MFMA GEMM (M=16384, K=1024, N=512) + fused LayerNorm.
// Block: 256 threads (4 waves), BM=64 rows, full 512 cols, BK=32.
// Wave w owns cols [w*128, w*128+128): 4 row-tiles x 8 col-tiles of 16x16.
// A fp32 sources converted to bf16 while staging; B pre-converted (Wt).
// LDS: A_lds 64x(32+8) bf16 (5 KB), B_lds 512x(32+8) bf16 (40 KB);
//      epilogue reuses LDS as 32x512 fp32 (64 KB), two halves.
// ---------------------------------------------------------------------------
#define ASTR 40   // padded k-stride (bf16 elems) for A/B LDS tiles
__global__ __launch_bounds__(256, 1)
void gemm_ln_mfma(const float* __restrict__ outp, const float* __restrict__ filt,
                  const unsigned short* __restrict__ Wt, const float* __restrict__ bcat,
                  const float* __restrict__ gamma, const float* __restrict__ beta,
                  float* __restrict__ out) {
    extern __shared__ unsigned char smc[];
    unsigned short* A_lds = (unsigned short*)smc;            // 64*40*2 = 5120 B
    unsigned short* B_lds = (unsigned short*)(smc + 5120);   // 512*40*2 = 40960 B
    float* ep = (float*)smc;                                 // epilogue 32*512*4 = 64 KB

    const int tid = threadIdx.x;
    const int lane = tid & 63;
    const int wv = tid >> 6;
    const int quad = lane >> 4;
    const int l15 = lane & 15;
    const int r0 = blockIdx.x * 64;

    floatx4 acc[4][8];
#pragma unroll
    for (int rt = 0; rt < 4; ++rt)
#pragma unroll
        for (int ct = 0; ct < 8; ++ct)
            acc[rt][ct] = (floatx4){0.f, 0.f, 0.f, 0.f};

    float bc[8];
#pragma unroll
    for (int ct = 0; ct < 8; ++ct) bc[ct] = bcat[wv * 128 + ct * 16 + l15];

    const int arow = tid >> 2;       // 0..63
    const int akp  = tid & 3;        // k-part (8 k's each)

    for (int kt = 0; kt < 32; ++kt) {
        const int kc = kt * 32;
        __syncthreads();
        // ---- stage A (64 rows x 32 k), fp32 -> bf16 ----
        {
            const float* src = (kc < 512) ? (outp + (size_t)(r0 + arow) * 512 + kc + akp * 8)
                                          : (filt + (size_t)(r0 + arow) * 512 + (kc - 512) + akp * 8);
            float4 v0 = *(const float4*)(src);
            float4 v1 = *(const float4*)(src + 4);
            unsigned int p0 = (unsigned int)f2bf(v0.x) | ((unsigned int)f2bf(v0.y) << 16);
            unsigned int p1 = (unsigned int)f2bf(v0.z) | ((unsigned int)f2bf(v0.w) << 16);
            unsigned int p2 = (unsigned int)f2bf(v1.x) | ((unsigned int)f2bf(v1.y) << 16);
            unsigned int p3 = (unsigned int)f2bf(v1.z) | ((unsigned int)f2bf(v1.w) << 16);
            uint4 pk = make_uint4(p0, p1, p2, p3);
            *(uint4*)(A_lds + arow * ASTR + akp * 8) = pk;
        }
        // ---- stage B (512 cols x 32 k), already bf16 ----
#pragma unroll
        for (int it = 0; it < 8; ++it) {
            int g = it * 256 + tid;
            int col = g >> 2, sub = g & 3;
            uint4 w = *(const uint4*)(Wt + (size_t)col * 1024 + kc + sub * 8);
            *(uint4*)(B_lds + col * ASTR + sub * 8) = w;
        }
        __syncthreads();
        // ---- fragments + MFMA ----
        short8 afr[4], bfr[8];
#pragma unroll
        for (int rt = 0; rt < 4; ++rt)
            afr[rt] = *(const short8*)(A_lds + (rt * 16 + l15) * ASTR + quad * 8);
#pragma unroll
        for (int ct = 0; ct < 8; ++ct)
            bfr[ct] = *(const short8*)(B_lds + (wv * 128 + ct * 16 + l15) * ASTR + quad * 8);
#pragma unroll
        for (int rt = 0; rt < 4; ++rt)
#pragma unroll
            for (int ct = 0; ct < 8; ++ct)
                acc[rt][ct] = __builtin_amdgcn_mfma_f32_16x16x32_bf16(afr[rt], bfr[ct],
                                                                     acc[rt][ct], 0, 0, 0);
    }

    // ---- epilogue: bias + LayerNorm, two 32-row halves through LDS ----
    for (int half = 0; half < 2; ++half) {
        __syncthreads();
#pragma unroll
        for (int rt2 = 0; rt2 < 2; ++rt2) {
            int rt = half * 2 + rt2;
#pragma unroll
            for (int ct = 0; ct < 8; ++ct) {
                int col = wv * 128 + ct * 16 + l15;
#pragma unroll
                for (int i = 0; i < 4; ++i) {
                    int row_l = rt2 * 16 + quad * 4 + i;
                    ep[row_l * 512 + col] = acc[rt][ct][i] + bc[ct];
                }
            }
        }
        __syncthreads();
        // LN: wave wv handles rows wv*8 .. wv*8+7 of this 32-row half
        for (int m8 = 0; m8 < 8; ++m8) {
            int m = wv * 8 + m8;
            float s = 0.0f, ss = 0.0f;
#pragma unroll
            for (int i = 0; i < 8; ++i) {
                float v = ep[m * 512 + i * 64 + lane];
                s += v; ss += v * v;
            }
#pragma unroll
            for (int o = 32; o >= 1; o >>= 1) {
                s += __shfl_down(s, o, 64);
                ss += __shfl_down(ss, o, 64);
            }
            s = __shfl(s, 0, 64);
            ss = __shfl(ss, 0, 64);
            float mu = s * (1.0f / 512.0f);
            float var = ss * (1.0f / 512.0f) - mu * mu;
            float rs = rsqrtf(var + 1e-5f);
            int r = r0 + half * 32 + m;
#pragma unroll
            for (int i = 0; i < 8; ++i) {
                int d = i * 64 + lane;
                float v = (ep[m * 512 + d] - mu) * rs * gamma[d] + beta[d];
                out[(size_t)r * 512 + d] = v;
            }
        }
    }
}

// ---------------------------------------------------------------------------
// Launch
// ---------------------------------------------------------------------------
extern "C" void kernel_launch(void* const* d_in, const int* in_sizes, int n_in,
                              void* d_out, int out_size, void* d_ws, size_t ws_size,
                              hipStream_t stream) {
    const float* output       = (const float*)d_in[0];
    const float* attn         = (const float*)d_in[1];
    const float* oeh          = (const float*)d_in[2];
    const int*   edge_index   = (const int*)d_in[3];
    const float* W_gcn        = (const float*)d_in[6];
    const float* b_gcn        = (const float*)d_in[7];
    const float* W_lin        = (const float*)d_in[8];
    const float* b_lin        = (const float*)d_in[9];
    const float* W_cheb       = (const float*)d_in[10];
    const float* b_cheb       = (const float*)d_in[11];
    const float* W_cat        = (const float*)d_in[12];
    const float* b_cat        = (const float*)d_in[13];
    const float* gamma        = (const float*)d_in[14];
    const float* beta         = (const float*)d_in[15];
    float* out = (float*)d_out;

    const int E = in_sizes[3] / 2;               // 262144 base edges
    const int* srcp = edge_index;
    const int* dstp = edge_index + E;

    uint8_t* ws = (uint8_t*)d_ws;
    size_t cur = 0;
    auto alloc = [&](size_t bytes) -> void* {
        void* p = ws + cur;
        cur += (bytes + 255) & ~(size_t)255;
        return p;
    };
    int*   cnt     = (int*)alloc(TOTALq * sizeof(int));
    int*   off     = (int*)alloc((TOTALq + 1) * sizeof(int));
    float* dinv_n  = (float*)alloc(TOTALq * sizeof(float));
    int*   csr_src = (int*)alloc((size_t)E * sizeof(int));
    float* csr_w   = (float*)alloc((size_t)E * sizeof(float));
    float* coeff   = (float*)alloc(Hq * Bq * 4 * sizeof(float));
    float* T1      = (float*)alloc((size_t)NTq * DHq * sizeof(float));
    float* T2      = (float*)alloc((size_t)NTq * DHq * sizeof(float));
    float* filt    = (float*)alloc((size_t)TOTALq * Dq * sizeof(float));
    unsigned short* Wt = (unsigned short*)alloc((size_t)Dq * 1024 * sizeof(unsigned short));
    (void)ws_size; (void)n_in; (void)out_size;

    hipMemsetAsync(cnt, 0, TOTALq * sizeof(int), stream);
    count_deg_kernel<<<(E + 255) / 256, 256, 0, stream>>>(dstp, cnt, E);
    dinv_kernel<<<TOTALq / 256, 256, 0, stream>>>(cnt, dinv_n);
    scan_kernel<<<1, 1024, 0, stream>>>(cnt, off);
    scatter_kernel<<<(E + 255) / 256, 256, 0, stream>>>(srcp, dstp, off, cnt, dinv_n,
                                                        csr_src, csr_w, E);
    coeff_kernel<<<Hq * Bq, 256, 0, stream>>>(attn, W_gcn, b_gcn, W_lin, b_lin, coeff);

    // W_cat transpose+bf16 (can overlap with graph kernels on the same stream)
    dim3 wtg(16, 8);
    wt_kernel<<<wtg, 256, 0, stream>>>(W_cat, Wt);

    const int cheb_blocks = NTq / 4;  // 4 waves per 256-thread block
    cheb01_kernel<<<cheb_blocks, 256, 0, stream>>>(oeh, off, csr_src, csr_w, coeff,
                                                   W_cheb, T1, filt);
    chebstep_kernel<<<cheb_blocks, 256, 0, stream>>>(oeh, off, csr_src, csr_w, coeff,
                                                     W_cheb + 2 * DHq * DHq,
                                                     T1, nullptr, T2, b_cheb, filt,
                                                     2, 1, 1, 0);
    chebstep_kernel<<<cheb_blocks, 256, 0, stream>>>(oeh, off, csr_src, csr_w, coeff,
                                                     W_cheb + 3 * DHq * DHq,
                                                     T2, T1, nullptr, b_cheb, filt,
                                                     3, 0, 0, 1);

    gemm_ln_mfma<<<TOTALq / 64, 256, 65536, stream>>>(output, filt, Wt, b_cat,
                                                      gamma, beta, out);
}

// Round 3
// 497.983 us; speedup vs baseline: 28.3311x; 3.2250x over previous
//
#include <hip/hip_runtime.h>
#include <stdint.h>

// Problem constants (fixed by the reference):
#define Bq      64
#define Nq      256
#define Hq      8
#define DHq     64
#define TOTALq  16384    // B*N
#define NTq     131072   // H*TOTAL
#define Dq      512      // H*DH

typedef __attribute__((ext_vector_type(8))) short short8;
typedef __attribute__((ext_vector_type(4))) float floatx4;

__device__ __forceinline__ unsigned short f2bf(float f) {
    union { float f; unsigned int u; } c; c.f = f;
    unsigned int u = c.u;
    return (unsigned short)((u + 0x7fffu + ((u >> 16) & 1u)) >> 16);
}
__device__ __forceinline__ float bf2f(unsigned short u) {
    union { unsigned int u; float f; } c; c.u = ((unsigned int)u) << 16;
    return c.f;
}

// ---------------------------------------------------------------------------
// Graph structure: degree -> dinv; dense per-sample P (64 x 256 x 256)
// P[g][d][s] += -(dinv[s]*dinv[d]) per edge (handles duplicates like segment_sum)
// ---------------------------------------------------------------------------

__global__ void count_deg_kernel(const int* __restrict__ dstp, int* __restrict__ cnt, int E) {
    int e = blockIdx.x * 256 + threadIdx.x;
    if (e < E) atomicAdd(&cnt[dstp[e]], 1);
}

__global__ void dinv_kernel(const int* __restrict__ cnt, float* __restrict__ dinv_n) {
    int v = blockIdx.x * 256 + threadIdx.x;
    if (v < TOTALq) {
        int c = cnt[v];
        dinv_n[v] = (c > 0) ? rsqrtf((float)c) : 0.0f;
    }
}

__global__ void pscatter_kernel(const int* __restrict__ srcp, const int* __restrict__ dstp,
                                const float* __restrict__ dinv_n, float* __restrict__ Pf, int E) {
    int e = blockIdx.x * 256 + threadIdx.x;
    if (e >= E) return;
    int s = srcp[e], d = dstp[e];
    int g = d >> 8;  // sample index (s and d are in the same sample by construction)
    atomicAdd(&Pf[((size_t)g << 16) + ((size_t)(d & 255) << 8) + (s & 255)],
              -(dinv_n[s] * dinv_n[d]));
}

__global__ void pconv_kernel(const float* __restrict__ Pf, unsigned short* __restrict__ Pb) {
    int i = (blockIdx.x * 256 + threadIdx.x) * 4;
    float4 v = *(const float4*)(Pf + i);
    unsigned int lo = (unsigned int)f2bf(v.x) | ((unsigned int)f2bf(v.y) << 16);
    unsigned int hi = (unsigned int)f2bf(v.z) | ((unsigned int)f2bf(v.w) << 16);
    *(uint2*)(Pb + i) = make_uint2(lo, hi);
}

// ---------------------------------------------------------------------------
// oeh (16384 x 512 fp32, col = h*64+dh) -> X0_t (512 x 16384 bf16), transposed
// grid (256, 8), 64x64 tiles
// ---------------------------------------------------------------------------
__global__ void x0t_kernel(const float* __restrict__ X, unsigned short* __restrict__ Xt) {
    __shared__ float tile[64 * 68];
    int t = threadIdx.x;
    int n0 = blockIdx.x * 64, c0 = blockIdx.y * 64;
#pragma unroll
    for (int it = 0; it < 4; ++it) {
        int idx = it * 256 + t;
        int nr = idx >> 4, sub = idx & 15;
        float4 v = *(const float4*)(X + (size_t)(n0 + nr) * 512 + c0 + sub * 4);
        *(float4*)(&tile[nr * 68 + sub * 4]) = v;
    }
    __syncthreads();
#pragma unroll
    for (int it = 0; it < 2; ++it) {
        int idx = it * 256 + t;
        int cr = idx >> 3, sub = idx & 7;
        unsigned int pk[4];
#pragma unroll
        for (int q = 0; q < 4; ++q) {
            unsigned short a = f2bf(tile[(sub * 8 + q * 2 + 0) * 68 + cr]);
            unsigned short b = f2bf(tile[(sub * 8 + q * 2 + 1) * 68 + cr]);
            pk[q] = (unsigned int)a | ((unsigned int)b << 16);
        }
        *(uint4*)(Xt + (size_t)(c0 + cr) * 16384 + n0 + sub * 8) =
            make_uint4(pk[0], pk[1], pk[2], pk[3]);
    }
}

// bf16 transpose: Tt (512 x 16384) -> Tn (16384 x 512). grid (256, 8)
__global__ void trn_kernel(const unsigned short* __restrict__ Tt, unsigned short* __restrict__ Tn) {
    __shared__ unsigned short tile[64 * 72];
    int t = threadIdx.x;
    int n0 = blockIdx.x * 64, c0 = blockIdx.y * 64;
#pragma unroll
    for (int it = 0; it < 2; ++it) {
        int idx = it * 256 + t;
        int cr = idx >> 3, sub = idx & 7;
        uint4 v = *(const uint4*)(Tt + (size_t)(c0 + cr) * 16384 + n0 + sub * 8);
        *(uint4*)(&tile[cr * 72 + sub * 8]) = v;
    }
    __syncthreads();
#pragma unroll
    for (int it = 0; it < 2; ++it) {
        int idx = it * 256 + t;
        int nr = idx >> 3, sub = idx & 7;
        unsigned int pk[4];
#pragma unroll
        for (int q = 0; q < 4; ++q) {
            unsigned short a = tile[(sub * 8 + q * 2 + 0) * 72 + nr];
            unsigned short b = tile[(sub * 8 + q * 2 + 1) * 72 + nr];
            pk[q] = (unsigned int)a | ((unsigned int)b << 16);
        }
        *(uint4*)(Tn + (size_t)(n0 + nr) * 512 + c0 + sub * 8) =
            make_uint4(pk[0], pk[1], pk[2], pk[3]);
    }
}

// W_cheb (4 x 64 x 64, [k][j][n]) -> WchT bf16 [k][n][j]
__global__ void wchebt_kernel(const float* __restrict__ W, unsigned short* __restrict__ WT) {
    int idx = blockIdx.x * 256 + threadIdx.x;  // 16384 total
    int k = idx >> 12, rem = idx & 4095;
    int n = rem >> 6, j = rem & 63;
    WT[idx] = f2bf(W[(k << 12) + (j << 6) + n]);
}

// ---------------------------------------------------------------------------
// Coefficient kernel: one block per graph g = h*B + b (512 blocks, 256 thr)
// ---------------------------------------------------------------------------
__global__ void coeff_kernel(const float* __restrict__ attn,
                             const float* __restrict__ Wg, const float* __restrict__ bg,
                             const float* __restrict__ Wlin, const float* __restrict__ blin,
                             float* __restrict__ coeff) {
    __shared__ float dinv[Nq];
    __shared__ float red[16];
    int g = blockIdx.x;
    int h = g >> 6;
    int b = g & 63;
    const float* A = attn + ((size_t)(b * Hq + h)) * (Nq * Nq);
    int j = threadIdx.x;

    float cs = 0.0f;
    for (int i = 0; i < Nq; ++i) cs += A[i * Nq + j];
    float dv = rsqrtf(cs + 1.0f);
    dinv[j] = dv;
    __syncthreads();

    float sj = dv;
    for (int i = 0; i < Nq; ++i) sj += dinv[i] * A[i * Nq + j];
    sj *= dv;

    float xc[4];
#pragma unroll
    for (int c = 0; c < 4; ++c) {
        float wr = Wg[0 * 4 + c] + Wg[1 * 4 + c] + Wg[2 * 4 + c] + Wg[3 * 4 + c];
        xc[c] = tanhf(sj * wr + bg[c]);
    }
    int lane = j & 63, wv = j >> 6;
#pragma unroll
    for (int c = 0; c < 4; ++c) {
        float v = xc[c];
#pragma unroll
        for (int o = 32; o >= 1; o >>= 1) v += __shfl_down(v, o, 64);
        if (lane == 0) red[wv * 4 + c] = v;
    }
    __syncthreads();
    if (j < 4) {
        float gap[4];
#pragma unroll
        for (int c = 0; c < 4; ++c)
            gap[c] = (red[0 + c] + red[4 + c] + red[8 + c] + red[12 + c]) * (1.0f / 256.0f);
        float v = blin[j];
#pragma unroll
        for (int c = 0; c < 4; ++c) v += gap[c] * Wlin[c * 4 + j];
        coeff[g * 4 + j] = v;
    }
}

// ---------------------------------------------------------------------------
// Chebyshev propagation via per-sample dense MFMA GEMM.
// Tn_t[col][node] = first ? (P_b @ Tc)  :  2*(P_b @ Tc) - Tp
// grid (64 samples, 2 row-halves, 4 col-blocks); 256 thr; BM=128,BN=128,BK=32
// ---------------------------------------------------------------------------
__global__ __launch_bounds__(256, 2)
void cheb_prop(const unsigned short* __restrict__ Pb,
               const unsigned short* __restrict__ Tc,
               const unsigned short* __restrict__ Tp,
               unsigned short* __restrict__ Tn, int first) {
    __shared__ unsigned short A_lds[128 * 40];
    __shared__ unsigned short B_lds[128 * 40];
    const int b = blockIdx.x, mb = blockIdx.y, cb = blockIdx.z;
    const int tid = threadIdx.x, lane = tid & 63, wv = tid >> 6;
    const int wr = wv & 1, wc = wv >> 1, quad = lane >> 4, l15 = lane & 15;
    const unsigned short* Pbase = Pb + ((size_t)b << 16) + (size_t)mb * 128 * 256;

    floatx4 acc[4][4];
#pragma unroll
    for (int rt = 0; rt < 4; ++rt)
#pragma unroll
        for (int ct = 0; ct < 4; ++ct) acc[rt][ct] = (floatx4){0.f, 0.f, 0.f, 0.f};

    for (int kt = 0; kt < 8; ++kt) {
        const int kc = kt * 32;
        __syncthreads();
#pragma unroll
        for (int it = 0; it < 2; ++it) {
            int idx = it * 256 + tid;
            int row = idx >> 2, sub = idx & 3;
            *(uint4*)(A_lds + row * 40 + sub * 8) =
                *(const uint4*)(Pbase + row * 256 + kc + sub * 8);
            *(uint4*)(B_lds + row * 40 + sub * 8) =
                *(const uint4*)(Tc + (size_t)(cb * 128 + row) * 16384 + b * 256 + kc + sub * 8);
        }
        __syncthreads();
        short8 af[4], bfr[4];
#pragma unroll
        for (int rt = 0; rt < 4; ++rt)
            af[rt] = *(const short8*)(A_lds + (wr * 64 + rt * 16 + l15) * 40 + quad * 8);
#pragma unroll
        for (int ct = 0; ct < 4; ++ct)
            bfr[ct] = *(const short8*)(B_lds + (wc * 64 + ct * 16 + l15) * 40 + quad * 8);
#pragma unroll
        for (int rt = 0; rt < 4; ++rt)
#pragma unroll
            for (int ct = 0; ct < 4; ++ct)
                acc[rt][ct] = __builtin_amdgcn_mfma_f32_16x16x32_bf16(af[rt], bfr[ct],
                                                                     acc[rt][ct], 0, 0, 0);
    }
#pragma unroll
    for (int rt = 0; rt < 4; ++rt)
#pragma unroll
        for (int ct = 0; ct < 4; ++ct) {
            int col = cb * 128 + wc * 64 + ct * 16 + l15;
            int m = mb * 128 + wr * 64 + rt * 16 + quad * 4;
            size_t base = (size_t)col * 16384 + b * 256 + m;
            float v[4];
            if (first) {
#pragma unroll
                for (int i = 0; i < 4; ++i) v[i] = acc[rt][ct][i];
            } else {
                uint2 tp = *(const uint2*)(Tp + base);
                v[0] = 2.0f * acc[rt][ct][0] - bf2f((unsigned short)(tp.x & 0xffff));
                v[1] = 2.0f * acc[rt][ct][1] - bf2f((unsigned short)(tp.x >> 16));
                v[2] = 2.0f * acc[rt][ct][2] - bf2f((unsigned short)(tp.y & 0xffff));
                v[3] = 2.0f * acc[rt][ct][3] - bf2f((unsigned short)(tp.y >> 16));
            }
            unsigned int lo = (unsigned int)f2bf(v[0]) | ((unsigned int)f2bf(v[1]) << 16);
            unsigned int hi = (unsigned int)f2bf(v[2]) | ((unsigned int)f2bf(v[3]) << 16);
            *(uint2*)(Tn + base) = make_uint2(lo, hi);
        }
}

// ---------------------------------------------------------------------------
// filt[(n*B+b)*512 + h*64 + c] = b_cheb[c] + sum_k ck(h,b) * (T_k @ W_cheb[k])
// grid (64 samples, 8 heads); 256 thr. A = ck*T_k (256x64), B = W_k^T (64x64)
// ---------------------------------------------------------------------------
__global__ __launch_bounds__(256, 2)
void filt_kernel(const float* __restrict__ oeh,
                 const unsigned short* __restrict__ T1n, const unsigned short* __restrict__ T2n,
                 const unsigned short* __restrict__ T3n, const unsigned short* __restrict__ WchT,
                 const float* __restrict__ coeff, const float* __restrict__ bch,
                 float* __restrict__ filt) {
    __shared__ unsigned short A_lds[256 * 72];  // 36 KB
    __shared__ unsigned short W_lds[64 * 72];   // 9 KB
    const int b = blockIdx.x, h = blockIdx.y;
    const int tid = threadIdx.x, lane = tid & 63, wv = tid >> 6;
    const int quad = lane >> 4, l15 = lane & 15;

    floatx4 acc[4][4];
#pragma unroll
    for (int rt = 0; rt < 4; ++rt)
#pragma unroll
        for (int ct = 0; ct < 4; ++ct) acc[rt][ct] = (floatx4){0.f, 0.f, 0.f, 0.f};

    for (int k = 0; k < 4; ++k) {
        float ck = coeff[(h * Bq + b) * 4 + k];
        __syncthreads();
        if (k == 0) {
#pragma unroll
            for (int it = 0; it < 8; ++it) {
                int idx = it * 256 + tid;
                int row = idx >> 3, sub = idx & 7;
                const float* sp = oeh + (size_t)(b * 256 + row) * 512 + h * 64 + sub * 8;
                float4 v0 = *(const float4*)sp;
                float4 v1 = *(const float4*)(sp + 4);
                unsigned int p0 = (unsigned int)f2bf(v0.x * ck) | ((unsigned int)f2bf(v0.y * ck) << 16);
                unsigned int p1 = (unsigned int)f2bf(v0.z * ck) | ((unsigned int)f2bf(v0.w * ck) << 16);
                unsigned int p2 = (unsigned int)f2bf(v1.x * ck) | ((unsigned int)f2bf(v1.y * ck) << 16);
                unsigned int p3 = (unsigned int)f2bf(v1.z * ck) | ((unsigned int)f2bf(v1.w * ck) << 16);
                *(uint4*)(A_lds + row * 72 + sub * 8) = make_uint4(p0, p1, p2, p3);
            }
        } else {
            const unsigned short* Tk = (k == 1) ? T1n : (k == 2) ? T2n : T3n;
#pragma unroll
            for (int it = 0; it < 8; ++it) {
                int idx = it * 256 + tid;
                int row = idx >> 3, sub = idx & 7;
                uint4 tv = *(const uint4*)(Tk + (size_t)(b * 256 + row) * 512 + h * 64 + sub * 8);
                unsigned int w[4] = {tv.x, tv.y, tv.z, tv.w};
                unsigned int o[4];
#pragma unroll
                for (int q = 0; q < 4; ++q) {
                    float lo = bf2f((unsigned short)(w[q] & 0xffff)) * ck;
                    float hi = bf2f((unsigned short)(w[q] >> 16)) * ck;
                    o[q] = (unsigned int)f2bf(lo) | ((unsigned int)f2bf(hi) << 16);
                }
                *(uint4*)(A_lds + row * 72 + sub * 8) = make_uint4(o[0], o[1], o[2], o[3]);
            }
        }
#pragma unroll
        for (int it = 0; it < 2; ++it) {
            int idx = it * 256 + tid;
            int r = idx >> 3, sub = idx & 7;
            *(uint4*)(W_lds + r * 72 + sub * 8) =
                *(const uint4*)(WchT + k * 4096 + r * 64 + sub * 8);
        }
        __syncthreads();
#pragma unroll
        for (int kk = 0; kk < 2; ++kk) {
            short8 af[4], bfr[4];
#pragma unroll
            for (int rt = 0; rt < 4; ++rt)
                af[rt] = *(const short8*)(A_lds + (wv * 64 + rt * 16 + l15) * 72 + kk * 32 + quad * 8);
#pragma unroll
            for (int ct = 0; ct < 4; ++ct)
                bfr[ct] = *(const short8*)(W_lds + (ct * 16 + l15) * 72 + kk * 32 + quad * 8);
#pragma unroll
            for (int rt = 0; rt < 4; ++rt)
#pragma unroll
                for (int ct = 0; ct < 4; ++ct)
                    acc[rt][ct] = __builtin_amdgcn_mfma_f32_16x16x32_bf16(af[rt], bfr[ct],
                                                                         acc[rt][ct], 0, 0, 0);
        }
    }
#pragma unroll
    for (int rt = 0; rt < 4; ++rt)
#pragma unroll
        for (int ct = 0; ct < 4; ++ct) {
            int coln = ct * 16 + l15;
            float bias = bch[coln];
#pragma unroll
            for (int i = 0; i < 4; ++i) {
                int m = wv * 64 + rt * 16 + quad * 4 + i;  // local node n
                size_t r = (size_t)m * 64 + b;             // n*B + b
                filt[r * 512 + h * 64 + coln] = acc[rt][ct][i] + bias;
            }
        }
}

// ---------------------------------------------------------------------------
// W_cat transpose+convert: W (1024x512 fp32) -> Wt (512x1024 bf16)
// ---------------------------------------------------------------------------
__global__ void wt_kernel(const float* __restrict__ W, unsigned short* __restrict__ Wt) {
    __shared__ float tile[64][65];
    int t = threadIdx.x;
    int k0 = blockIdx.x * 64;
    int c0 = blockIdx.y * 64;
#pragma unroll
    for (int it = 0; it < 16; ++it) {
        int idx = it * 256 + t;
        int kr = idx >> 6, cc = idx & 63;
        tile[kr][cc] = W[(size_t)(k0 + kr) * 512 + c0 + cc];
    }
    __syncthreads();
#pragma unroll
    for (int it = 0; it < 16; ++it) {
        int idx = it * 256 + t;
        int cr = idx >> 6, kk = idx & 63;
        Wt[(size_t)(c0 + cr) * 1024 + k0 + kk] = f2bf(tile[kk][cr]);
    }
}

// ---------------------------------------------------------------------------
// MFMA GEMM (M=16384, K=1024, N=512) + fused LayerNorm.
// ---------------------------------------------------------------------------
#define ASTR 40
__global__ __launch_bounds__(256, 1)
void gemm_ln_mfma(const float* __restrict__ outp, const float* __restrict__ filt,
                  const unsigned short* __restrict__ Wt, const float* __restrict__ bcat,
                  const float* __restrict__ gamma, const float* __restrict__ beta,
                  float* __restrict__ out) {
    extern __shared__ unsigned char smc[];
    unsigned short* A_lds = (unsigned short*)smc;
    unsigned short* B_lds = (unsigned short*)(smc + 5120);
    float* ep = (float*)smc;

    const int tid = threadIdx.x;
    const int lane = tid & 63;
    const int wv = tid >> 6;
    const int quad = lane >> 4;
    const int l15 = lane & 15;
    const int r0 = blockIdx.x * 64;

    floatx4 acc[4][8];
#pragma unroll
    for (int rt = 0; rt < 4; ++rt)
#pragma unroll
        for (int ct = 0; ct < 8; ++ct)
            acc[rt][ct] = (floatx4){0.f, 0.f, 0.f, 0.f};

    float bc[8];
#pragma unroll
    for (int ct = 0; ct < 8; ++ct) bc[ct] = bcat[wv * 128 + ct * 16 + l15];

    const int arow = tid >> 2;
    const int akp  = tid & 3;

    for (int kt = 0; kt < 32; ++kt) {
        const int kc = kt * 32;
        __syncthreads();
        {
            const float* src = (kc < 512) ? (outp + (size_t)(r0 + arow) * 512 + kc + akp * 8)
                                          : (filt + (size_t)(r0 + arow) * 512 + (kc - 512) + akp * 8);
            float4 v0 = *(const float4*)(src);
            float4 v1 = *(const float4*)(src + 4);
            unsigned int p0 = (unsigned int)f2bf(v0.x) | ((unsigned int)f2bf(v0.y) << 16);
            unsigned int p1 = (unsigned int)f2bf(v0.z) | ((unsigned int)f2bf(v0.w) << 16);
            unsigned int p2 = (unsigned int)f2bf(v1.x) | ((unsigned int)f2bf(v1.y) << 16);
            unsigned int p3 = (unsigned int)f2bf(v1.z) | ((unsigned int)f2bf(v1.w) << 16);
            *(uint4*)(A_lds + arow * ASTR + akp * 8) = make_uint4(p0, p1, p2, p3);
        }
#pragma unroll
        for (int it = 0; it < 8; ++it) {
            int g = it * 256 + tid;
            int col = g >> 2, sub = g & 3;
            uint4 w = *(const uint4*)(Wt + (size_t)col * 1024 + kc + sub * 8);
            *(uint4*)(B_lds + col * ASTR + sub * 8) = w;
        }
        __syncthreads();
        short8 afr[4], bfr[8];
#pragma unroll
        for (int rt = 0; rt < 4; ++rt)
            afr[rt] = *(const short8*)(A_lds + (rt * 16 + l15) * ASTR + quad * 8);
#pragma unroll
        for (int ct = 0; ct < 8; ++ct)
            bfr[ct] = *(const short8*)(B_lds + (wv * 128 + ct * 16 + l15) * ASTR + quad * 8);
#pragma unroll
        for (int rt = 0; rt < 4; ++rt)
#pragma unroll
            for (int ct = 0; ct < 8; ++ct)
                acc[rt][ct] = __builtin_amdgcn_mfma_f32_16x16x32_bf16(afr[rt], bfr[ct],
                                                                     acc[rt][ct], 0, 0, 0);
    }

    for (int half = 0; half < 2; ++half) {
        __syncthreads();
#pragma unroll
        for (int rt2 = 0; rt2 < 2; ++rt2) {
            int rt = half * 2 + rt2;
#pragma unroll
            for (int ct = 0; ct < 8; ++ct) {
                int col = wv * 128 + ct * 16 + l15;
#pragma unroll
                for (int i = 0; i < 4; ++i) {
                    int row_l = rt2 * 16 + quad * 4 + i;
                    ep[row_l * 512 + col] = acc[rt][ct][i] + bc[ct];
                }
            }
        }
        __syncthreads();
        for (int m8 = 0; m8 < 8; ++m8) {
            int m = wv * 8 + m8;
            float s = 0.0f, ss = 0.0f;
#pragma unroll
            for (int i = 0; i < 8; ++i) {
                float v = ep[m * 512 + i * 64 + lane];
                s += v; ss += v * v;
            }
#pragma unroll
            for (int o = 32; o >= 1; o >>= 1) {
                s += __shfl_down(s, o, 64);
                ss += __shfl_down(ss, o, 64);
            }
            s = __shfl(s, 0, 64);
            ss = __shfl(ss, 0, 64);
            float mu = s * (1.0f / 512.0f);
            float var = ss * (1.0f / 512.0f) - mu * mu;
            float rs = rsqrtf(var + 1e-5f);
            int r = r0 + half * 32 + m;
#pragma unroll
            for (int i = 0; i < 8; ++i) {
                int d = i * 64 + lane;
                float v = (ep[m * 512 + d] - mu) * rs * gamma[d] + beta[d];
                out[(size_t)r * 512 + d] = v;
            }
        }
    }
}

// ---------------------------------------------------------------------------
// Launch
// ---------------------------------------------------------------------------
extern "C" void kernel_launch(void* const* d_in, const int* in_sizes, int n_in,
                              void* d_out, int out_size, void* d_ws, size_t ws_size,
                              hipStream_t stream) {
    const float* output       = (const float*)d_in[0];
    const float* attn         = (const float*)d_in[1];
    const float* oeh          = (const float*)d_in[2];
    const int*   edge_index   = (const int*)d_in[3];
    const float* W_gcn        = (const float*)d_in[6];
    const float* b_gcn        = (const float*)d_in[7];
    const float* W_lin        = (const float*)d_in[8];
    const float* b_lin        = (const float*)d_in[9];
    const float* W_cheb       = (const float*)d_in[10];
    const float* b_cheb       = (const float*)d_in[11];
    const float* W_cat        = (const float*)d_in[12];
    const float* b_cat        = (const float*)d_in[13];
    const float* gamma        = (const float*)d_in[14];
    const float* beta         = (const float*)d_in[15];
    float* out = (float*)d_out;

    const int E = in_sizes[3] / 2;
    const int* srcp = edge_index;
    const int* dstp = edge_index + E;

    uint8_t* ws = (uint8_t*)d_ws;
    size_t cur = 0;
    auto alloc = [&](size_t bytes) -> void* {
        void* p = ws + cur;
        cur += (bytes + 255) & ~(size_t)255;
        return p;
    };
    int*   cnt     = (int*)alloc(TOTALq * sizeof(int));
    float* dinv_n  = (float*)alloc(TOTALq * sizeof(float));
    float* Pf      = (float*)alloc((size_t)64 * 65536 * sizeof(float));     // 16.8 MB
    unsigned short* Pb   = (unsigned short*)alloc((size_t)64 * 65536 * 2);  //  8.4 MB
    float* coeff   = (float*)alloc(512 * 4 * sizeof(float));
    unsigned short* X0_t = (unsigned short*)alloc((size_t)512 * 16384 * 2); // 16.8 MB
    unsigned short* T1_t = (unsigned short*)alloc((size_t)512 * 16384 * 2);
    unsigned short* T2_t = (unsigned short*)alloc((size_t)512 * 16384 * 2);
    unsigned short* T3_t = (unsigned short*)alloc((size_t)512 * 16384 * 2);
    unsigned short* WchT = (unsigned short*)alloc(4 * 64 * 64 * 2);
    unsigned short* Wt   = (unsigned short*)alloc((size_t)Dq * 1024 * 2);
    float* filt    = (float*)alloc((size_t)TOTALq * Dq * sizeof(float));
    // aliases into dead regions (lifetimes verified by launch order):
    unsigned short* T1_n = (unsigned short*)Pf;   // Pf dead after pconv
    unsigned short* T2_n = X0_t;                  // X0_t dead after prop2
    unsigned short* T3_n = T1_t;                  // T1_t dead after prop3+trn1
    (void)ws_size; (void)n_in; (void)out_size;

    hipMemsetAsync(cnt, 0, TOTALq * sizeof(int), stream);
    count_deg_kernel<<<(E + 255) / 256, 256, 0, stream>>>(dstp, cnt, E);
    dinv_kernel<<<TOTALq / 256, 256, 0, stream>>>(cnt, dinv_n);
    hipMemsetAsync(Pf, 0, (size_t)64 * 65536 * sizeof(float), stream);
    pscatter_kernel<<<(E + 255) / 256, 256, 0, stream>>>(srcp, dstp, dinv_n, Pf, E);
    pconv_kernel<<<4096, 256, 0, stream>>>(Pf, Pb);

    x0t_kernel<<<dim3(256, 8), 256, 0, stream>>>(oeh, X0_t);
    coeff_kernel<<<Hq * Bq, 256, 0, stream>>>(attn, W_gcn, b_gcn, W_lin, b_lin, coeff);
    wt_kernel<<<dim3(16, 8), 256, 0, stream>>>(W_cat, Wt);
    wchebt_kernel<<<64, 256, 0, stream>>>(W_cheb, WchT);

    dim3 pg(64, 2, 4);
    cheb_prop<<<pg, 256, 0, stream>>>(Pb, X0_t, nullptr, T1_t, 1);
    cheb_prop<<<pg, 256, 0, stream>>>(Pb, T1_t, X0_t, T2_t, 0);
    cheb_prop<<<pg, 256, 0, stream>>>(Pb, T2_t, T1_t, T3_t, 0);

    trn_kernel<<<dim3(256, 8), 256, 0, stream>>>(T1_t, T1_n);
    trn_kernel<<<dim3(256, 8), 256, 0, stream>>>(T2_t, T2_n);
    trn_kernel<<<dim3(256, 8), 256, 0, stream>>>(T3_t, T3_n);  // writes over T1_t (already consumed)

    filt_kernel<<<dim3(64, 8), 256, 0, stream>>>(oeh, T1_n, T2_n, T3_n, WchT, coeff,
                                                 b_cheb, filt);

    gemm_ln_mfma<<<TOTALq / 64, 256, 65536, stream>>>(output, filt, Wt, b_cat,
                                                      gamma, beta, out);
}